// Round 13
// baseline (80.628 us; speedup 1.0000x reference)
//
#include <hip/hip_runtime.h>
#include <stdint.h>

// Problem dims
#define NB   4096   // batch rows (M)
#define KD   2048   // IN + S   (K)
#define ND   4096   // 4*S      (N, reordered: n -> gate=(n>>4)&3, s=(n>>6)*16+(n&15))
#define SD   1024   // state size

// GEMM tile (256x256, 8 waves = 2M x 4N, m201 8-phase schedule, hoisted addrs)
#define BM   256
#define BN   256
#define BK   64
#define NKT  (KD / BK)   // 32 K-tiles

using f32x4  = __attribute__((ext_vector_type(4))) float;
using bf16x8 = __attribute__((ext_vector_type(8))) short;

typedef const __attribute__((address_space(1))) uint32_t* gas_u32;
typedef __attribute__((address_space(3))) uint32_t* las_u32;

__device__ __forceinline__ unsigned short f2bf(float f) {
    union { float f; uint32_t u; } c; c.f = f;
    uint32_t u = c.u;
    uint32_t r = (u + 0x7fffu + ((u >> 16) & 1u)) >> 16;  // RNE
    return (unsigned short)r;
}

__device__ __forceinline__ void async_load16(const void* gsrc, void* ldst) {
    __builtin_amdgcn_global_load_lds((gas_u32)gsrc, (las_u32)ldst, 16, 0, 0);
}

__device__ __forceinline__ float frcp(float x) { return __builtin_amdgcn_rcpf(x); }
__device__ __forceinline__ float sigm(float x) { return frcp(1.f + __expf(-x)); }
__device__ __forceinline__ float tanh_fast(float x) {
    return 1.f - 2.f * frcp(1.f + __expf(2.f * x));   // inf-safe
}

// ---------------------------------------------------------------------------
// Pack: fp32 -> bf16, X=[input|old_h]; W rows reordered so GEMM column
// n maps to weights row  gate*SD + (n>>6)*16 + (n&15),  gate=(n>>4)&3.
// ---------------------------------------------------------------------------
__global__ void pack_kernel(const float* __restrict__ input,
                            const float* __restrict__ old_h,
                            const float* __restrict__ weights,
                            const float* __restrict__ bias,
                            unsigned short* __restrict__ Xb,
                            unsigned short* __restrict__ Wb,
                            float* __restrict__ biasR) {
    const int XCH = NB * (KD / 4);
    const int WCH = ND * (KD / 4);
    const int BCH = ND / 4;
    const int total = XCH + WCH + BCH;
    for (int c = blockIdx.x * blockDim.x + threadIdx.x; c < total;
         c += gridDim.x * blockDim.x) {
        if (c < XCH) {
            int b  = c >> 9;
            int k  = (c & 511) << 2;
            const float* src = (k < 1024) ? (input + (size_t)b * 1024 + k)
                                          : (old_h + (size_t)b * 1024 + (k - 1024));
            float4 v = *reinterpret_cast<const float4*>(src);
            ushort4 o;
            o.x = f2bf(v.x); o.y = f2bf(v.y); o.z = f2bf(v.z); o.w = f2bf(v.w);
            *reinterpret_cast<ushort4*>(Xb + (size_t)b * KD + k) = o;
        } else if (c < XCH + WCH) {
            int cc = c - XCH;
            int n  = cc >> 9;
            int k  = (cc & 511) << 2;
            int srow = ((n >> 4) & 3) * SD + ((n >> 6) * 16 + (n & 15));
            float4 v = *reinterpret_cast<const float4*>(weights + (size_t)srow * KD + k);
            ushort4 o;
            o.x = f2bf(v.x); o.y = f2bf(v.y); o.z = f2bf(v.z); o.w = f2bf(v.w);
            *reinterpret_cast<ushort4*>(Wb + (size_t)n * KD + k) = o;
        } else {
            int n4 = (c - XCH - WCH) << 2;
            #pragma unroll
            for (int t = 0; t < 4; ++t) {
                int n = n4 + t;
                biasR[n] = bias[((n >> 4) & 3) * SD + ((n >> 6) * 16 + (n & 15))];
            }
        }
    }
}

// ---------------------------------------------------------------------------
// 256x256 GEMM + fused LSTM epilogue — R12's m201 8-phase schedule with ALL
// addresses hoisted out of the loop (HK technique #8):
//  * LDS reads: row&7 == l15&7 (rows offset by multiples of 8), so the XOR
//    swizzle is lane-constant -> 8 base-address VGPRs (vA/vB x db x kk);
//    every ds_read = base VGPR + compile-time immediate.
//    LDS layout: A regions at bytes [0,64K): (db*2+half)*16384;
//                B regions at [64K,128K): 65536 + (db*2+half)*16384.
//  * Staging: 4 per-thread base pointers; per-load addr = base +
//    compile-time half offset + kt*128 (SALU) -> ~4 VALU/phase.
// R12's VALUBusy=20% (~276 cyc/phase of serial address math between
// barriers) was the hidden serial term; schedule/waitcnts unchanged here.
// Ledger identical to R12 (stages P0/P1:A(T+1), P2/P3:B(T+2), P4/P5:A(T+2),
// P6/P7:B(T+3); vmcnt(4) @P3/P7; lgkm8 on 12-read phases; prologue
// B0,A0,B1 + vmcnt(4)).
// ---------------------------------------------------------------------------
#define LDS_A(DB, HALF) (((DB) * 2 + (HALF)) * 16384)
#define LDS_B(DB, HALF) (65536 + ((DB) * 2 + (HALF)) * 16384)

#define SBAR   __builtin_amdgcn_s_barrier()
#define LGKM8  asm volatile("s_waitcnt lgkmcnt(8)")
#define LGKM0  asm volatile("s_waitcnt lgkmcnt(0)")
#define VMC4   asm volatile("s_waitcnt vmcnt(4)" ::: "memory")
#define PRIO1  __builtin_amdgcn_s_setprio(1)
#define PRIO0  __builtin_amdgcn_s_setprio(0)

__launch_bounds__(512, 2)
__global__ void lstm_gemm(const unsigned short* __restrict__ Xb,
                          const unsigned short* __restrict__ Wb,
                          const float* __restrict__ biasR,
                          const float* __restrict__ old_cell,
                          float* __restrict__ new_h,
                          float* __restrict__ new_cell) {
    __shared__ unsigned short lds[65536];   // 128 KiB
    char* const ldsc = (char*)lds;

    const int tid  = threadIdx.x;
    const int lane = tid & 63;
    const int wid  = tid >> 6;       // 0..7
    const int wm   = wid >> 2;       // 0..1  (M half owner)
    const int wn   = wid & 3;        // 0..3  (N quarter owner)
    const int l15  = lane & 15;
    const int krow = lane >> 4;      // 0..3

    // XCD-aware bijective swizzle (256 blocks, 8 XCDs)
    const int wg    = blockIdx.x;
    const int swz   = (wg & 7) * 32 + (wg >> 3);
    const int mblk  = swz >> 4;
    const int nblk  = swz & 15;
    const int rbase = mblk * BM;
    const int nbase = nblk * BN;

    // ---- hoisted LDS read base addresses (bytes); swizzle is lane-constant:
    // row = (16*anything) + l15  =>  row&7 = l15&7
    const int lx   = l15 & 7;
    const int lrow = l15 * 128;
    const int sw0  = ((krow)     ^ lx) * 16;   // kk=0
    const int sw1  = ((krow + 4) ^ lx) * 16;   // kk=1
    const int vA00 = LDS_A(0, 0) + wm * 16384 + lrow + sw0;  // db0,kk0 (+wm half)
    const int vA01 = LDS_A(0, 0) + wm * 16384 + lrow + sw1;
    const int vA10 = LDS_A(1, 0) + wm * 16384 + lrow + sw0;
    const int vA11 = LDS_A(1, 0) + wm * 16384 + lrow + sw1;
    const int bpan = (wn >> 1) * 16384 + (wn & 1) * 8192;    // B half + 64-row sub
    const int vB00 = LDS_B(0, 0) + bpan + lrow + sw0;
    const int vB01 = LDS_B(0, 0) + bpan + lrow + sw1;
    const int vB10 = LDS_B(1, 0) + bpan + lrow + sw0;
    const int vB11 = LDS_B(1, 0) + bpan + lrow + sw1;

    // ---- hoisted staging addresses ----
    // chunk c0=tid, c1=tid+512; row=c>>3, src k-slot=(c&7)^(row&7)
    const int c0 = tid, c1 = tid + 512;
    const int srow0 = c0 >> 3, sk0 = ((c0 & 7) ^ (srow0 & 7)) * 8;
    const int srow1 = c1 >> 3, sk1 = ((c1 & 7) ^ (srow1 & 7)) * 8;
    const unsigned short* const pX0 = Xb + (size_t)(rbase + srow0) * KD + sk0;
    const unsigned short* const pX1 = Xb + (size_t)(rbase + srow1) * KD + sk1;
    const unsigned short* const pW0 = Wb + (size_t)(nbase + srow0) * KD + sk0;
    const unsigned short* const pW1 = Wb + (size_t)(nbase + srow1) * KD + sk1;
    const int ldst0 = tid * 16, ldst1 = tid * 16 + 8192;

    f32x4  acc[8][4] = {};
    bf16x8 a[4][2];        // A frags of current quadrant
    bf16x8 b0[2][2];       // B frags nq=0
    bf16x8 b1[2][2];       // B frags nq=1

    // half offset in elements is compile-time: HALF*128*KD
#define STAGE_X(KT, DB, HALF) do {                                              \
        async_load16(pX0 + (HALF) * 128 * KD + (KT) * BK, ldsc + LDS_A(DB, HALF) + ldst0); \
        async_load16(pX1 + (HALF) * 128 * KD + (KT) * BK, ldsc + LDS_A(DB, HALF) + ldst1); \
    } while (0)
#define STAGE_W(KT, DB, HALF) do {                                              \
        async_load16(pW0 + (HALF) * 128 * KD + (KT) * BK, ldsc + LDS_B(DB, HALF) + ldst0); \
        async_load16(pW1 + (HALF) * 128 * KD + (KT) * BK, ldsc + LDS_B(DB, HALF) + ldst1); \
    } while (0)

    // ds_read: base VGPR + compile-time immediate (MQ*8192 + i*2048)
#define LOAD_A(V0, V1, MQ) do {                                                 \
        _Pragma("unroll") for (int i_ = 0; i_ < 4; ++i_) {                      \
            a[i_][0] = *reinterpret_cast<const bf16x8*>(                        \
                ldsc + (V0) + (MQ) * 8192 + i_ * 2048);                         \
            a[i_][1] = *reinterpret_cast<const bf16x8*>(                        \
                ldsc + (V1) + (MQ) * 8192 + i_ * 2048);                         \
        }                                                                       \
    } while (0)
#define LOAD_B(DST, V0, V1, NQ) do {                                            \
        _Pragma("unroll") for (int j_ = 0; j_ < 2; ++j_) {                      \
            DST[j_][0] = *reinterpret_cast<const bf16x8*>(                      \
                ldsc + (V0) + (NQ) * 4096 + j_ * 2048);                         \
            DST[j_][1] = *reinterpret_cast<const bf16x8*>(                      \
                ldsc + (V1) + (NQ) * 4096 + j_ * 2048);                         \
        }                                                                       \
    } while (0)

#define MMA_Q(MQ, NQH, BB) do {                                                 \
        _Pragma("unroll") for (int i_ = 0; i_ < 4; ++i_)                        \
        _Pragma("unroll") for (int j_ = 0; j_ < 2; ++j_)                        \
        _Pragma("unroll") for (int kk_ = 0; kk_ < 2; ++kk_)                     \
            acc[(MQ) * 4 + i_][(NQH) * 2 + j_] =                                \
                __builtin_amdgcn_mfma_f32_16x16x32_bf16(                        \
                    a[i_][kk_], BB[j_][kk_],                                    \
                    acc[(MQ) * 4 + i_][(NQH) * 2 + j_], 0, 0, 0);               \
    } while (0)

    // ---- prologue: B(0),A(0) -> buf0; B(1) -> buf1; tile0 landed ----
    STAGE_W(0, 0, 0);
    STAGE_W(0, 0, 1);
    STAGE_X(0, 0, 0);
    STAGE_X(0, 0, 1);
    STAGE_W(1, 1, 0);
    STAGE_W(1, 1, 1);
    VMC4;    // 12 outstanding -> drain 8 = tile0 landed; B(1) in flight
    SBAR;

    // ---- main loop: 8 phases / 2 K-tiles (tile parity = buffer) ----
    for (int t = 0; t < NKT; t += 2) {
        const int kt1 = t + 1;
        const int kt2 = (t + 2) & (NKT - 1);
        const int kt3 = (t + 3) & (NKT - 1);

        // P0: tile T quadrant (0,0)
        LOAD_A(vA00, vA01, 0);
        LOAD_B(b0, vB00, vB01, 0);
        STAGE_X(kt1, 1, 0);
        LGKM8;
        SBAR; LGKM0; PRIO1; MMA_Q(0, 0, b0); PRIO0; SBAR;
        // P1: quadrant (0,1)
        LOAD_B(b1, vB00, vB01, 1);
        STAGE_X(kt1, 1, 1);
        SBAR; LGKM0; PRIO1; MMA_Q(0, 1, b1); PRIO0; SBAR;
        // P2: quadrant (1,0)
        LOAD_A(vA00, vA01, 1);
        STAGE_W(kt2, 0, 0);
        SBAR; LGKM0; PRIO1; MMA_Q(1, 0, b0); PRIO0; SBAR;
        // P3: quadrant (1,1); vmcnt gate for tile T+1
        STAGE_W(kt2, 0, 1);
        SBAR; LGKM0; PRIO1; MMA_Q(1, 1, b1); PRIO0; VMC4; SBAR;
        // P4: tile T+1 quadrant (0,0)
        LOAD_A(vA10, vA11, 0);
        LOAD_B(b0, vB10, vB11, 0);
        STAGE_X(kt2, 0, 0);
        LGKM8;
        SBAR; LGKM0; PRIO1; MMA_Q(0, 0, b0); PRIO0; SBAR;
        // P5: quadrant (0,1)
        LOAD_B(b1, vB10, vB11, 1);
        STAGE_X(kt2, 0, 1);
        SBAR; LGKM0; PRIO1; MMA_Q(0, 1, b1); PRIO0; SBAR;
        // P6: quadrant (1,0)
        LOAD_A(vA10, vA11, 1);
        STAGE_W(kt3, 1, 0);
        SBAR; LGKM0; PRIO1; MMA_Q(1, 0, b0); PRIO0; SBAR;
        // P7: quadrant (1,1); vmcnt gate for tile T+2
        STAGE_W(kt3, 1, 1);
        SBAR; LGKM0; PRIO1; MMA_Q(1, 1, b1); PRIO0; VMC4; SBAR;
    }

    // ---- fused LSTM epilogue (reg-resident, zero-shuffle) ----
    const int s = (nblk * 4 + wn) * 16 + l15;
    float bg[4];
    #pragma unroll
    for (int jj = 0; jj < 4; ++jj)
        bg[jj] = biasR[nbase + wn * 64 + jj * 16 + l15];

    #pragma unroll
    for (int mi = 0; mi < 8; ++mi) {
        #pragma unroll
        for (int r = 0; r < 4; ++r) {
            const int row = rbase + wm * 128 + mi * 16 + krow * 4 + r;
            float fg = sigm(acc[mi][0][r] + bg[0]);
            float ig = sigm(acc[mi][1][r] + bg[1]);
            float og = sigm(acc[mi][2][r] + bg[2]);
            float gg = tanh_fast(acc[mi][3][r] + bg[3]);
            float oc = old_cell[(size_t)row * SD + s];
            float nc = fmaf(fg, oc, ig * gg);
            float nh = og * tanh_fast(nc);
            new_h[(size_t)row * SD + s]    = nh;
            new_cell[(size_t)row * SD + s] = nc;
        }
    }
}

extern "C" void kernel_launch(void* const* d_in, const int* in_sizes, int n_in,
                              void* d_out, int out_size, void* d_ws, size_t ws_size,
                              hipStream_t stream) {
    const float* input    = (const float*)d_in[0];
    const float* old_h    = (const float*)d_in[1];
    const float* old_cell = (const float*)d_in[2];
    const float* weights  = (const float*)d_in[3];
    const float* bias     = (const float*)d_in[4];

    unsigned short* Xb  = (unsigned short*)d_ws;                             // 16 MiB
    unsigned short* Wb  = (unsigned short*)((char*)d_ws + (size_t)16777216); // 16 MiB
    float*          bR  = (float*)((char*)d_ws + (size_t)33554432);          // 16 KiB

    float* out_h = (float*)d_out;
    float* out_c = out_h + (size_t)NB * SD;

    pack_kernel<<<2048, 256, 0, stream>>>(input, old_h, weights, bias, Xb, Wb, bR);
    lstm_gemm<<<(NB / BM) * (ND / BN), 512, 0, stream>>>(Xb, Wb, bR, old_cell,
                                                         out_h, out_c);
}